// Round 1
// baseline (48.435 us; speedup 1.0000x reference)
//
#include <hip/hip_runtime.h>

#define IMG_H 512
#define IMG_W 512
#define CH    3
#define TILE  16
#define PAD   2
#define TP    (TILE + 2 * PAD)   // 20

__device__ __forceinline__ int reflect_idx(int i, int n) {
    i = (i < 0) ? -i : i;
    i = (i >= n) ? (2 * n - 2 - i) : i;
    return i;
}

__global__ __launch_bounds__(256)
void bilateral_kernel(const float* __restrict__ in, float* __restrict__ out) {
    __shared__ float lds[TP][TP][CH];

    const int b  = blockIdx.z;
    const int by = blockIdx.y * TILE;
    const int bx = blockIdx.x * TILE;
    const int tx = threadIdx.x;
    const int ty = threadIdx.y;
    const int tid = ty * TILE + tx;

    // Cooperative load of the (TP x TP) halo tile with reflect padding.
    for (int i = tid; i < TP * TP; i += 256) {
        const int py = i / TP;
        const int px = i - py * TP;
        const int gy = reflect_idx(by + py - PAD, IMG_H);
        const int gx = reflect_idx(bx + px - PAD, IMG_W);
        const float* src = in + ((size_t)(b * IMG_H + gy) * IMG_W + gx) * CH;
        lds[py][px][0] = src[0];
        lds[py][px][1] = src[1];
        lds[py][px][2] = src[2];
    }
    __syncthreads();

    // Spatial Gaussian (sigma_s = 1.0, k = 5), normalized. exp(-2), exp(-0.5).
    const float e2  = 0.13533528323661270f;
    const float e05 = 0.60653065971263342f;
    const float gi  = 1.0f / (1.0f + 2.0f * e2 + 2.0f * e05);
    const float gv[5] = { e2 * gi, e05 * gi, gi, e05 * gi, e2 * gi };

    const float c0 = lds[ty + PAD][tx + PAD][0];
    const float c1 = lds[ty + PAD][tx + PAD][1];
    const float c2 = lds[ty + PAD][tx + PAD][2];

    const float K = -0.5f / (0.04f * 0.04f);   // -1/(2*sigma_r^2) = -312.5

    float n0 = 0.0f, n1 = 0.0f, n2 = 0.0f, den = 0.0f;

    #pragma unroll
    for (int dy = 0; dy < 5; ++dy) {
        const float gdy = gv[dy];
        #pragma unroll
        for (int dx = 0; dx < 5; ++dx) {
            const float s0 = lds[ty + dy][tx + dx][0];
            const float s1 = lds[ty + dy][tx + dx][1];
            const float s2 = lds[ty + dy][tx + dx][2];
            const float d0 = s0 - c0;
            const float d1 = s1 - c1;
            const float d2 = s2 - c2;
            const float dist2 = fmaf(d0, d0, fmaf(d1, d1, d2 * d2));
            const float w = gdy * gv[dx] * __expf(K * dist2);
            n0 = fmaf(w, s0, n0);
            n1 = fmaf(w, s1, n1);
            n2 = fmaf(w, s2, n2);
            den += w;
        }
    }

    const float inv = 1.0f / den;
    const int y = by + ty;
    const int x = bx + tx;
    float* dst = out + ((size_t)(b * IMG_H + y) * IMG_W + x) * CH;
    dst[0] = fminf(fmaxf(n0 * inv, 0.0f), 1.0f);
    dst[1] = fminf(fmaxf(n1 * inv, 0.0f), 1.0f);
    dst[2] = fminf(fmaxf(n2 * inv, 0.0f), 1.0f);
}

extern "C" void kernel_launch(void* const* d_in, const int* in_sizes, int n_in,
                              void* d_out, int out_size, void* d_ws, size_t ws_size,
                              hipStream_t stream) {
    const float* in = (const float*)d_in[0];
    float* out = (float*)d_out;
    const int B = in_sizes[0] / (IMG_H * IMG_W * CH);   // 16

    dim3 block(TILE, TILE, 1);
    dim3 grid(IMG_W / TILE, IMG_H / TILE, B);           // 32 x 32 x 16
    bilateral_kernel<<<grid, block, 0, stream>>>(in, out);
}

// Round 2
// 40.721 us; speedup vs baseline: 1.1894x; 1.1894x over previous
//
#include <hip/hip_runtime.h>
#include <math.h>

#define IMG_H 512
#define IMG_W 512
#define CH    3
#define TILE  16
#define PAD   2
#define TP    (TILE + 2 * PAD)   // 20

#if __has_builtin(__builtin_amdgcn_exp2f)
#define EXP2(x) __builtin_amdgcn_exp2f(x)
#else
#define EXP2(x) exp2f(x)
#endif

#if __has_builtin(__builtin_amdgcn_rcpf)
#define RCP(x) __builtin_amdgcn_rcpf(x)
#else
#define RCP(x) (1.0f / (x))
#endif

__device__ __forceinline__ int reflect_idx(int i, int n) {
    i = (i < 0) ? -i : i;
    i = (i >= n) ? (2 * n - 2 - i) : i;
    return i;
}

__global__ __launch_bounds__(256)
void bilateral_kernel(const float* __restrict__ in, float* __restrict__ out) {
    // Each entry: {r*S, g*S, b*S, -(r*S)^2-(g*S)^2-(b*S)^2}, S^2 = 312.5*log2(e).
    // Row stride = 20 float4 = 80 dwords == 16 (mod 32): a wave's 64 b128 reads
    // hit every bank exactly 8x -> conflict-free minimum (8 cyc / 1 KiB).
    __shared__ float4 lds[TP][TP];

    const float S2   = 312.5f * 1.44269504088896f;  // K * log2(e) = 450.8422
    const float S    = sqrtf(S2);                    // compile-time folded
    const float invS = 1.0f / S;

    const int b  = blockIdx.z;
    const int by = blockIdx.y * TILE;
    const int bx = blockIdx.x * TILE;
    const int tx = threadIdx.x;
    const int ty = threadIdx.y;
    const int tid = ty * TILE + tx;

    // Cooperative halo load with reflect padding (2 iterations: 400/256).
    for (int i = tid; i < TP * TP; i += 256) {
        const int py = i / TP;
        const int px = i - py * TP;
        const int gy = reflect_idx(by + py - PAD, IMG_H);
        const int gx = reflect_idx(bx + px - PAD, IMG_W);
        const float* src = in + ((size_t)(b * IMG_H + gy) * IMG_W + gx) * CH;
        const float s0 = src[0] * S;
        const float s1 = src[1] * S;
        const float s2 = src[2] * S;
        const float mq = -fmaf(s0, s0, fmaf(s1, s1, s2 * s2));
        ((float4*)lds)[i] = make_float4(s0, s1, s2, mq);
    }
    __syncthreads();

    const float4 c = lds[ty + PAD][tx + PAD];
    const float c20 = c.x + c.x;
    const float c21 = c.y + c.y;
    const float c22 = c.z + c.z;

    // log2(sk[iy]*sk[ix]) for iy,ix = min(d,4-d); sk = normalized gaussian
    // weights {e^-2, e^-.5, 1}/sum. Precomputed literals.
    const float Cw00 = -8.395800f;   // log2(gv0*gv0)
    const float Cw01 = -6.231757f;
    const float Cw02 = -5.510409f;
    const float Cw11 = -4.067714f;
    const float Cw12 = -3.346367f;
    const float Cw22 = -2.625024f;

    // A[iy][ix] = Cw + (-q_center); all indices below are compile-time.
    const float A[3][3] = {
        { Cw00 + c.w, Cw01 + c.w, Cw02 + c.w },
        { Cw01 + c.w, Cw11 + c.w, Cw12 + c.w },
        { Cw02 + c.w, Cw12 + c.w, Cw22 + c.w },
    };

    float n0 = 0.0f, n1 = 0.0f, n2 = 0.0f, den = 0.0f;

    #pragma unroll
    for (int dy = 0; dy < 5; ++dy) {
        #pragma unroll
        for (int dx = 0; dx < 5; ++dx) {
            const int iy = (dy < 3) ? dy : 4 - dy;
            const int ix = (dx < 3) ? dx : 4 - dx;
            const float4 s = lds[ty + dy][tx + dx];
            // arg = log2(w_spatial) - S2*||s-c||^2  (expanded, fma chain)
            const float arg = fmaf(s.x, c20,
                              fmaf(s.y, c21,
                              fmaf(s.z, c22, A[iy][ix] + s.w)));
            const float w = EXP2(arg);
            n0 = fmaf(w, s.x, n0);
            n1 = fmaf(w, s.y, n1);
            n2 = fmaf(w, s.z, n2);
            den += w;
        }
    }

    // out = (n / den) * (1/S), clamped to [0,1]
    const float inv = RCP(den * S);
    const int y = by + ty;
    const int x = bx + tx;
    float* dst = out + ((size_t)(b * IMG_H + y) * IMG_W + x) * CH;
    dst[0] = fminf(fmaxf(n0 * inv, 0.0f), 1.0f);
    dst[1] = fminf(fmaxf(n1 * inv, 0.0f), 1.0f);
    dst[2] = fminf(fmaxf(n2 * inv, 0.0f), 1.0f);
}

extern "C" void kernel_launch(void* const* d_in, const int* in_sizes, int n_in,
                              void* d_out, int out_size, void* d_ws, size_t ws_size,
                              hipStream_t stream) {
    const float* in = (const float*)d_in[0];
    float* out = (float*)d_out;
    const int B = in_sizes[0] / (IMG_H * IMG_W * CH);   // 16

    dim3 block(TILE, TILE, 1);
    dim3 grid(IMG_W / TILE, IMG_H / TILE, B);           // 32 x 32 x 16
    bilateral_kernel<<<grid, block, 0, stream>>>(in, out);
}